// Round 6
// baseline (141.245 us; speedup 1.0000x reference)
//
#include <hip/hip_runtime.h>

typedef short s16x4 __attribute__((ext_vector_type(4)));
typedef short s16x8 __attribute__((ext_vector_type(8)));
typedef float f32x2 __attribute__((ext_vector_type(2)));
typedef float f32x16 __attribute__((ext_vector_type(16)));
typedef unsigned int u32x2 __attribute__((ext_vector_type(2)));
typedef unsigned int u32x4 __attribute__((ext_vector_type(4)));

#define HT_STRIDE 72  // bf16 row stride: 144 B = 9*16 -> 16B-aligned b128 rows

__device__ __forceinline__ unsigned short f2bf(float f) {
    unsigned int u = __float_as_uint(f);
    u += 0x7fffu + ((u >> 16) & 1u);
    return (unsigned short)(u >> 16);
}
__device__ __forceinline__ unsigned int pk2bf_rne(float lo, float hi) {
    unsigned int a = __float_as_uint(lo);
    a += 0x7fffu + ((a >> 16) & 1u);
    unsigned int b = __float_as_uint(hi);
    b += 0x7fffu + ((b >> 16) & 1u);
    return (a >> 16) | (b & 0xffff0000u);
}

// Inline-asm 16B global load: issue point is pinned in program order (memory
// clobber + sched_barrier fences) so neither the scheduler nor regalloc can
// collapse the prefetch distance — the failure mode of rounds 3/4.
#define GLOADX4(dst, base, OFF)                                       \
    asm volatile("global_load_dwordx4 %0, %1, off offset:" OFF        \
                 : "=&v"(dst) : "v"(base) : "memory")

// Factorization: T_l[(o,j),d] = sum_i W_l[o, i*64+j] * x[i,d]  (GEMM, K=i=64)
// A-frag prepack for 32x32x16: rows m = j_local (j = jt*32 + m), k = i.
// Wp frag index F = ((l*64+o)*2+jt)*4+ks ; value[lane][t] =
//   bf16( W_l[o][ (16*ks + 8*(lane>>5) + t)*64 + jt*32 + (lane&31) ] )
__global__ __launch_bounds__(256) void prepack_kernel(const float* __restrict__ W1,
                                                      const float* __restrict__ W2,
                                                      unsigned short* __restrict__ Wp) {
    int tid = blockIdx.x * 256 + threadIdx.x; // 0..65535, one 16B frag slice each
    int lane = tid & 63;
    int ks = (tid >> 6) & 3;
    int jt = (tid >> 8) & 1;
    int o = (tid >> 9) & 63;
    int l = tid >> 15;
    int q2 = lane >> 5;
    int n31 = lane & 31;
    const float* W = l ? W2 : W1;
    const float* base = W + o * 4096 + jt * 32 + n31;
    int i0 = 16 * ks + 8 * q2;
    float v[8];
#pragma unroll
    for (int t = 0; t < 8; ++t) v[t] = base[(i0 + t) * 64];
    u32x4 pv;
    pv[0] = pk2bf_rne(v[0], v[1]);
    pv[1] = pk2bf_rne(v[2], v[3]);
    pv[2] = pk2bf_rne(v[4], v[5]);
    pv[3] = pk2bf_rne(v[6], v[7]);
    ((u32x4*)Wp)[tid] = pv;
}

// Block = 1 batch elem, 4 waves, wave w owns o ≡ w (mod 4), both d-halves.
// Rounds 0-4: pinned at ~72-76 µs by loaded-L2 latency on the A-frag loads
// (per-it period 1400 cyc vs ~400 cyc of work; C-level prefetch distance is
// collapsed by regalloc). Round 5 (global_load_lds ping-pong) raced — the
// primitive is unverified here. THIS version: depth-3 prefetch via inline-asm
// global_load_dwordx4 into a 4-slot register ring, counted s_waitcnt
// vmcnt(12/8/4/0) + sched_barrier(0) fences (rule-#18 discipline). The wait
// constants are robust: vmcnt(4k) retires everything older than the 4k
// youngest VMEM ops, which always includes the current group.
__global__ __launch_bounds__(256, 2) void cin_kernel(const float* __restrict__ x,
                                                     const unsigned short* __restrict__ Wp,
                                                     const float* __restrict__ b1,
                                                     const float* __restrict__ b2,
                                                     const float* __restrict__ Wfc,
                                                     const float* __restrict__ bfc,
                                                     float* __restrict__ out) {
    // sH[l][d*72 + j]: layer-l j-factor source (l=0: x, l=1: h1), bf16 transposed
    __shared__ __align__(16) unsigned short sH[2][64 * HT_STRIDE]; // 18.4 KB
    __shared__ float sBias[128], sWfc[128], sRed[4];

    const int tid = threadIdx.x;
    const int w = tid >> 6;
    const int lane = tid & 63;
    const int q2 = lane >> 5;
    const int n31 = lane & 31;
    const int oh = w; // o ≡ oh (mod 4)
    const int bb = blockIdx.x;
    const char* WpB = (const char*)Wp;

    // ---- stage x: coalesced float4 reads -> transposed bf16 LDS ----
    {
        const float4* xb4 = (const float4*)(x + bb * 4096);
#pragma unroll
        for (int rr = 0; rr < 4; ++rr) {
            int e4 = rr * 256 + tid;
            float4 v = xb4[e4];
            int e = e4 << 2;
            int f = e >> 6;     // field index (i / j)
            int d0 = e & 63;    // d-index
            sH[0][(d0 + 0) * HT_STRIDE + f] = f2bf(v.x);
            sH[0][(d0 + 1) * HT_STRIDE + f] = f2bf(v.y);
            sH[0][(d0 + 2) * HT_STRIDE + f] = f2bf(v.z);
            sH[0][(d0 + 3) * HT_STRIDE + f] = f2bf(v.w);
        }
    }
    if (tid < 128) {
        sBias[tid] = (tid < 64) ? b1[tid] : b2[tid - 64];
        sWfc[tid] = Wfc[tid];
    }
    __syncthreads();

    const f32x16 zz = {};
    float contrib = 0.0f;

    // ---- A-frag ring: 4 slots x 4 frags, asm-loaded (64 VGPR, really live) --
    s16x8 Ar[4][4];

    // ---- prologue: issue groups 0,1,2 (l=0, it=0..2) into slots 0,1,2 ----
#pragma unroll
    for (int g0 = 0; g0 < 3; ++g0) {
        const int F = (8 * (g0 >> 1) + 2 * oh + (g0 & 1)) * 4;
        const char* gp = WpB + (size_t)F * 1024 + lane * 16;
        GLOADX4(Ar[g0][0], gp, "0");
        GLOADX4(Ar[g0][1], gp, "1024");
        GLOADX4(Ar[g0][2], gp, "2048");
        GLOADX4(Ar[g0][3], gp, "3072");
    }
    __builtin_amdgcn_sched_barrier(0);

    // ---- MFMA B-frags: B[k=i][n=d] = x[i,d] — fixed for BOTH layers ----
    // (these ds_reads overlap with the in-flight prologue loads)
    s16x8 bfr[2][4]; // [nt][ks]
#pragma unroll
    for (int nt = 0; nt < 2; ++nt) {
        const int d = nt * 32 + n31;
#pragma unroll
        for (int ks = 0; ks < 4; ++ks)
            bfr[nt][ks] = *(const s16x8*)&sH[0][d * HT_STRIDE + 16 * ks + 8 * q2];
    }

// consume one n-tile: weighted column-sum over the tile's 32 j-rows.
// cwp holds bf16 PAIRS; unpack = shift/mask (bf16 -> f32 is <<16).
#define CONSUME(NT, ACC, JT, O)                                                   \
    {                                                                             \
        const f32x2* a2 = (const f32x2*)&(ACC);                                   \
        f32x2 s0 = {0.0f, 0.0f}, s1 = {0.0f, 0.0f};                               \
        _Pragma("unroll") for (int m = 0; m < 4; ++m) {                           \
            unsigned int qlo = cwp[NT][JT][m][0];                                 \
            unsigned int qhi = cwp[NT][JT][m][1];                                 \
            f32x2 c0 = {__uint_as_float(qlo << 16),                               \
                        __uint_as_float(qlo & 0xffff0000u)};                      \
            f32x2 c1 = {__uint_as_float(qhi << 16),                               \
                        __uint_as_float(qhi & 0xffff0000u)};                      \
            s0 += a2[2 * m] * c0;                                                 \
            s1 += a2[2 * m + 1] * c1;                                             \
        }                                                                         \
        f32x2 s = s0 + s1;                                                        \
        if ((JT) == 0) {                                                          \
            hp[NT] = s;                                                           \
        } else {                                                                  \
            f32x2 t2 = hp[NT] + s;                                                \
            float hsum = t2.x + t2.y;                                             \
            hsum += __shfl_xor(hsum, 32, 64); /* partner q2-half rows */          \
            float v = fmaxf(hsum + sBias[l * 64 + (O)], 0.0f);                    \
            contrib += v * sWfc[l * 64 + (O)];                                    \
            if (l == 0) /* h1 handoff (both q2 halves write identical bits) */    \
                sH[1][((NT) * 32 + n31) * HT_STRIDE + (O)] = f2bf(v);             \
        }                                                                         \
    }

// One iteration, compile-time slot S = it&3 (passed literally: no runtime
// indexing of Ar -> no scratch). Prefetch group g+3 into slot (S+3)&3; its
// previous contents (group g-1) were consumed last iteration.
#define ITER(IT, S)                                                               \
    {                                                                             \
        const int it_ = (IT);                                                     \
        const int jt = it_ & 1;                                                   \
        const int o = 4 * (it_ >> 1) + oh;                                        \
        const int g = l * 32 + it_;                                               \
        if (g < 61) {                                                             \
            const int gn = g + 3;                                                 \
            const int ln = gn >> 5, itn = gn & 31;                                \
            const int Fn = (ln * 128 + 8 * (itn >> 1) + 2 * oh + (itn & 1)) * 4;  \
            const char* gp = WpB + (size_t)Fn * 1024 + lane * 16;                 \
            GLOADX4(Ar[((S) + 3) & 3][0], gp, "0");                               \
            GLOADX4(Ar[((S) + 3) & 3][1], gp, "1024");                            \
            GLOADX4(Ar[((S) + 3) & 3][2], gp, "2048");                            \
            GLOADX4(Ar[((S) + 3) & 3][3], gp, "3072");                            \
        }                                                                         \
        __builtin_amdgcn_sched_barrier(0);                                        \
        if (g < 61) {                                                             \
            asm volatile("s_waitcnt vmcnt(12)" ::: "memory");                     \
        } else if (g == 61) {                                                     \
            asm volatile("s_waitcnt vmcnt(8)" ::: "memory");                      \
        } else if (g == 62) {                                                     \
            asm volatile("s_waitcnt vmcnt(4)" ::: "memory");                      \
        } else {                                                                  \
            asm volatile("s_waitcnt vmcnt(0)" ::: "memory");                      \
        }                                                                         \
        __builtin_amdgcn_sched_barrier(0);                                        \
        const s16x8* A = Ar[(S)];                                                 \
        f32x16 a0 = __builtin_amdgcn_mfma_f32_32x32x16_bf16(A[0], bfr[0][0], zz, 0, 0, 0); \
        f32x16 a1 = __builtin_amdgcn_mfma_f32_32x32x16_bf16(A[0], bfr[1][0], zz, 0, 0, 0); \
        _Pragma("unroll") for (int ks = 1; ks < 4; ++ks) {                        \
            a0 = __builtin_amdgcn_mfma_f32_32x32x16_bf16(A[ks], bfr[0][ks], a0, 0, 0, 0); \
            a1 = __builtin_amdgcn_mfma_f32_32x32x16_bf16(A[ks], bfr[1][ks], a1, 0, 0, 0); \
        }                                                                         \
        CONSUME(0, a0, jt, o);                                                    \
        CONSUME(1, a1, jt, o);                                                    \
    }

    for (int l = 0; l < 2; ++l) {
        if (l) __syncthreads(); // h1 writes complete (the barrier's vmcnt drain
                                // also retires the cross-layer prefetches;
                                // counted waits then pass trivially — safe)

        // ---- per-layer consume weights (j-factor), PACKED bf16 pairs ----
        const unsigned short* hsrc = sH[l];
        u32x2 cwp[2][2][4]; // [nt][jt][m] = h[j= jt*32+4*q2+8*m+(0..3), d] pairs
#pragma unroll
        for (int nt = 0; nt < 2; ++nt) {
            const int d = nt * 32 + n31;
#pragma unroll
            for (int jt = 0; jt < 2; ++jt)
#pragma unroll
                for (int m = 0; m < 4; ++m)
                    cwp[nt][jt][m] =
                        *(const u32x2*)&hsrc[d * HT_STRIDE + jt * 32 + 4 * q2 + 8 * m];
        }

        f32x2 hp[2];

        for (int itb = 0; itb < 32; itb += 4) { // manual 4x unroll: literal slots
            ITER(itb + 0, 0);
            ITER(itb + 1, 1);
            ITER(itb + 2, 2);
            ITER(itb + 3, 3);
        }
    }
#undef ITER
#undef CONSUME

    // each (o,d) accumulated by both q2 halves -> halve at the end
    contrib *= 0.5f;
#pragma unroll
    for (int off = 32; off > 0; off >>= 1)
        contrib += __shfl_down(contrib, off, 64);
    if (lane == 0) sRed[w] = contrib;
    __syncthreads();
    if (tid == 0)
        out[bb] = (sRed[0] + sRed[1]) + (sRed[2] + sRed[3]) + bfc[0];
}

extern "C" void kernel_launch(void* const* d_in, const int* in_sizes, int n_in,
                              void* d_out, int out_size, void* d_ws, size_t ws_size,
                              hipStream_t stream) {
    const float* x = (const float*)d_in[0];
    const float* W1 = (const float*)d_in[1];
    const float* b1 = (const float*)d_in[2];
    const float* W2 = (const float*)d_in[3];
    const float* b2 = (const float*)d_in[4];
    const float* Wfc = (const float*)d_in[5];
    const float* bfc = (const float*)d_in[6];
    float* out = (float*)d_out;

    unsigned short* Wp = (unsigned short*)d_ws; // 524288 bf16 = 1 MB prepacked W'

    prepack_kernel<<<256, 256, 0, stream>>>(W1, W2, Wp);
    cin_kernel<<<1024, 256, 0, stream>>>(x, Wp, b1, b2, Wfc, bfc, out);
}